// Round 8
// baseline (225.040 us; speedup 1.0000x reference)
//
#include <hip/hip_runtime.h>

// DenseLayerWithComplexNeurons: out = per-cell-type-MLP( x @ W^T + b )
// M = B*S = 8192, K = DIN = 1024, N = A*DOUT = 4096, DOUT = 1024
//
// R1: 128x128/BK64 + fused LDS epilogue. 154.5us, 2.5e7 conflicts.
// R2: XOR-swizzled staging -> 0 conflicts, 118.9us.
// R3: 256x128, 128x64 wave tiles, 32x32x16 MFMA. 101.2us.
// R4: 256x256, 128KB dbuf, 1 block/CU. 115.6us REGRESSION. TLP > dbuf.
// R5: R3 + BK=32 dbuf. 103.4us; bad swizzle -> 3x conflicts.
// R6: fixed swizzle (r>>1)&3. 94.7us. 2 waves/SIMD (acc counts vs unified RF).
// R7: 64x64 tiles, 4 waves/SIMD. 105.2us REGRESSION: +33% LDS frag traffic.
//     R4+R7 bracket: occupancy doesn't move the wall, LDS bytes/FLOP does.
// R8: B never touches LDS. Weights repacked [K/8][N][8] so B-fragments are
//     single coalesced global_load_dwordx4 (32 lanes = 512B contig) into
//     VGPRs, register-double-buffered one full iteration ahead (L2-resident,
//     latency hidden). LDS = A only (dbuf 2x8KB). L2 pipe takes B's ~30us,
//     LDS pipe drops to ~25us total. 64x64 tiles, acc 64 -> 3 waves/SIMD.

typedef __bf16 bf16x8 __attribute__((ext_vector_type(8)));
typedef float f32x4 __attribute__((ext_vector_type(4)));
typedef float f32x16 __attribute__((ext_vector_type(16)));

#define BM 128
#define BN 128
#define BK 32
#define KDIM 1024
#define NDIM 4096
#define NITER (KDIM / BK)    // 32
#define ABUF_B 8192          // bytes per A LDS buffer (128 rows x 64 B)
#define XN8 (8192 * 1024 / 8)
#define WN8 (4096 * 1024 / 8)

// x -> xb (bf16, same layout); w [N][K] -> wbp bf16 packed [K/8][N][8]
__global__ __launch_bounds__(256) void cvt_pack_kernel(
    const float* __restrict__ x, const float* __restrict__ w,
    __bf16* __restrict__ xb, __bf16* __restrict__ wbp) {
    int i = blockIdx.x * 256 + threadIdx.x;
    if (i < XN8) {
        const f32x4* p = (const f32x4*)x + 2 * (size_t)i;
        f32x4 a = p[0], b = p[1];
        bf16x8 o;
        o[0]=(__bf16)a[0]; o[1]=(__bf16)a[1]; o[2]=(__bf16)a[2]; o[3]=(__bf16)a[3];
        o[4]=(__bf16)b[0]; o[5]=(__bf16)b[1]; o[6]=(__bf16)b[2]; o[7]=(__bf16)b[3];
        ((bf16x8*)xb)[i] = o;
    } else {
        const int j  = i - XN8;      // j = n*128 + k8 (reads coalesced over k8)
        const int n  = j >> 7;
        const int k8 = j & 127;
        const f32x4* p = (const f32x4*)(w + (size_t)n * KDIM + k8 * 8);
        f32x4 a = p[0], b = p[1];
        bf16x8 o;
        o[0]=(__bf16)a[0]; o[1]=(__bf16)a[1]; o[2]=(__bf16)a[2]; o[3]=(__bf16)a[3];
        o[4]=(__bf16)b[0]; o[5]=(__bf16)b[1]; o[6]=(__bf16)b[2]; o[7]=(__bf16)b[3];
        ((bf16x8*)wbp)[(size_t)k8 * NDIM + n] = o;   // 16B scattered writes
    }
}

union __align__(16) SmemU {
    __bf16 stg[2 * (ABUF_B / 2)];  // 16 KB: two A buffers (128 rows x 64 B),
                                   // 16B chunk c of row r at slot c^((r>>1)&3)
    float  z[64 * 128];            // one 64-row slab; neuron g of row r at
                                   // 16B-chunk (g+(r&3))&31 (32 KB, aliases)
};

__global__ __launch_bounds__(256) void fused_gemm_mlp_kernel(
    const __bf16* __restrict__ Ag,   // [8192][1024] bf16 (x)
    const __bf16* __restrict__ Bw,   // packed [K/8][4096][8] bf16 weights
    const float* __restrict__ bias,  // [4096]
    const float* __restrict__ cw1,   // [4][4][8]
    const float* __restrict__ cb1,   // [4][8]
    const float* __restrict__ cw2,   // [4][8]
    const float* __restrict__ cb2,   // [4]
    float* __restrict__ out)         // [8192][1024]
{
    __shared__ SmemU u;

    const int tid  = threadIdx.x;
    const int wave = tid >> 6;
    const int lane = tid & 63;
    const int wm = wave >> 1;        // row half (0..1): 64 rows each
    const int wn = wave & 1;         // col half (0..1): 64 cols each
    const int bn0 = blockIdx.x * BN;
    const int bm0 = blockIdx.y * BM;

    f32x16 acc[2][2] = {};           // 2x2 tiles of 32x32

    // A staging lane map (16-row/1KB chunks, XOR swizzle)
    const int srow4 = lane >> 2;
    const int g8    = (((lane & 3) ^ ((lane >> 3) & 3)) * 8);

    // A fragment addressing
    const int lr5 = lane & 31;
    const int lk2 = lane >> 5;       // 0..1
    const int sw2 = (lr5 >> 1) & 3;
    const int arow = (wm * 64 + lr5) * (BK * 2);   // bytes within buffer
    int cxo[2];
#pragma unroll
    for (int kh = 0; kh < 2; ++kh)
        cxo[kh] = ((kh * 2 + lk2) ^ sw2) * 16;
    const char* sb = (const char*)u.stg;

    // B fragment per-lane element offset into packed [K/8][N][8]:
    // frag(kh,ni) at row (k0/8 + kh*2 + lk2), col (bn0 + wn*64 + ni*32 + lr5)
    const size_t bvoff = ((size_t)lk2 * NDIM + bn0 + wn * 64 + lr5) * 8;

    const __bf16* aBase = Ag + (size_t)(bm0 + wave * 32 + srow4) * KDIM + g8;

    auto stage = [&](int it, int buf) {
        __bf16* dstA = u.stg + buf * (ABUF_B / 2);
        const int kof = it * BK;
#pragma unroll
        for (int c = 0; c < 2; ++c) {   // 8 chunks of 16 rows, 2 per wave
            __builtin_amdgcn_global_load_lds(
                (__attribute__((address_space(1))) void*)(aBase + (size_t)c * 16 * KDIM + kof),
                (__attribute__((address_space(3))) void*)&dstA[(wave * 2 + c) * 512],
                16, 0, 0);
        }
    };

    auto loadB = [&](int it, bf16x8 b[2][2]) {
        const __bf16* bp = Bw + (size_t)it * 4 * NDIM * 8 + bvoff;
#pragma unroll
        for (int kh = 0; kh < 2; ++kh)
#pragma unroll
            for (int ni = 0; ni < 2; ++ni)
                b[kh][ni] = *(const bf16x8*)(bp + (size_t)kh * 2 * NDIM * 8 + ni * 32 * 8);
    };

    auto compute = [&](int buf, const bf16x8 b[2][2]) {
        const char* base = sb + buf * ABUF_B;
#pragma unroll
        for (int kh = 0; kh < 2; ++kh) {
            bf16x8 af[2];
#pragma unroll
            for (int mi = 0; mi < 2; ++mi)
                af[mi] = *(const bf16x8*)(base + arow + mi * 2048 + cxo[kh]);
#pragma unroll
            for (int mi = 0; mi < 2; ++mi)
#pragma unroll
                for (int ni = 0; ni < 2; ++ni)
                    acc[mi][ni] = __builtin_amdgcn_mfma_f32_32x32x16_bf16(
                        af[mi], b[kh][ni], acc[mi][ni], 0, 0, 0);
        }
    };

    bf16x8 b0[2][2], b1[2][2];
    stage(0, 0);
    loadB(0, b0);
#pragma unroll 1
    for (int it = 0; it < NITER; it += 2) {
        // barrier vmcnt(0) drains stage(it)+loadB(it): both issued a full
        // compute phase ago. Buffer !(it&1) no longer read -> safe to fill.
        __syncthreads();
        stage(it + 1, 1);
        loadB(it + 1, b1);
        compute(0, b0);
        __syncthreads();
        if (it + 2 < NITER) {
            stage(it + 2, 0);
            loadB(it + 2, b0);
        }
        compute(1, b1);
    }
    __syncthreads();  // all LDS reads done before z overwrites stg

    // ---- epilogue: per-neuron MLP over A=4 adjacent z columns ----
    const int t = bn0 >> 10;  // cell type, block-uniform
    const float L2E2 = 2.885390081777927f;  // 2*log2(e)
    float oinit = cb2[t];
#pragma unroll
    for (int i = 0; i < 8; ++i) oinit += cw2[t * 8 + i];

    float bcol[2];
#pragma unroll
    for (int ni = 0; ni < 2; ++ni)
        bcol[ni] = bias[bn0 + wn * 64 + ni * 32 + lr5];

#pragma unroll
    for (int h = 0; h < 2; ++h) {  // 64-row slabs
        if (wm == h) {
#pragma unroll
            for (int mi = 0; mi < 2; ++mi) {
#pragma unroll
                for (int ni = 0; ni < 2; ++ni) {
                    const int n  = wn * 64 + ni * 32 + lr5;
                    const int gc = n >> 2;       // neuron within block
                    const int a  = n & 3;        // arity slot
#pragma unroll
                    for (int g = 0; g < 4; ++g) {
                        // C/D 32x32: col=lane&31, row=(reg&3)+8*(reg>>2)+4*(lane>>5)
                        const int rb = mi * 32 + g * 8 + lk2 * 4;
#pragma unroll
                        for (int j = 0; j < 4; ++j) {
                            const int chunk = (gc + j) & 31;  // (r&3)==j
                            u.z[(rb + j) * 128 + chunk * 4 + a] =
                                acc[mi][ni][g * 4 + j] + bcol[ni];
                        }
                    }
                }
            }
        }
        __syncthreads();

        // 64 rows x 32 neurons = 2048 outputs; 8/thread
#pragma unroll
        for (int it2 = 0; it2 < 8; ++it2) {
            const int i = tid + it2 * 256;
            const int q = (i & 7) + 8 * ((i >> 8) & 3);
            const int r = ((i >> 3) & 31) + 32 * (i >> 10);
            const int chunk = (q + (r & 3)) & 31;
            f32x4 z = *(const f32x4*)&u.z[r * 128 + chunk * 4];
            float o = oinit;
#pragma unroll
            for (int hh = 0; hh < 8; ++hh) {
                float pre = z[0] * cw1[t * 32 + 0 * 8 + hh] + z[1] * cw1[t * 32 + 1 * 8 + hh]
                          + z[2] * cw1[t * 32 + 2 * 8 + hh] + z[3] * cw1[t * 32 + 3 * 8 + hh]
                          + cb1[t * 8 + hh];
                float e = __builtin_amdgcn_exp2f(pre * L2E2);       // e^(2*pre)
                o -= 2.0f * cw2[t * 8 + hh] * __builtin_amdgcn_rcpf(e + 1.0f);
            }
            out[(size_t)(bm0 + h * 64 + r) * 1024 + (bn0 >> 2) + q] = o;
        }
        __syncthreads();
    }
}

extern "C" void kernel_launch(void* const* d_in, const int* in_sizes, int n_in,
                              void* d_out, int out_size, void* d_ws, size_t ws_size,
                              hipStream_t stream) {
    const float* x    = (const float*)d_in[0];
    const float* w    = (const float*)d_in[1];
    const float* bias = (const float*)d_in[2];
    const float* cw1  = (const float*)d_in[3];
    const float* cb1  = (const float*)d_in[4];
    const float* cw2  = (const float*)d_in[5];
    const float* cb2  = (const float*)d_in[6];
    float* out = (float*)d_out;

    __bf16* xb  = (__bf16*)d_ws;                      // 16 MB
    __bf16* wbp = xb + (size_t)8192 * 1024;           // 8 MB packed weights

    cvt_pack_kernel<<<(XN8 + WN8) / 256, 256, 0, stream>>>(x, w, xb, wbp);

    dim3 grid(4096 / BN, 8192 / BM);  // (32, 64) = 2048 blocks
    fused_gemm_mlp_kernel<<<grid, 256, 0, stream>>>(xb, wbp, bias, cw1, cb1, cw2, cb2, out);
}